// Round 2
// baseline (1718.442 us; speedup 1.0000x reference)
//
#include <hip/hip_runtime.h>
#include <hip/hip_bf16.h>

// B=256, N=H=512, C=A=64, L=3, FC=256, FFC=32.  M := B*C = 16384 "rows" of xm.
// All device tensors are FP32 (per the jnp.float32 reference). Intermediates fp32 in d_ws.

// ---------------- transpose: x[b,n,c] (f32) -> xm[(b*64+c)*512+n] (f32)
__global__ __launch_bounds__(256) void k_transpose(const float* __restrict__ x, float* __restrict__ xm) {
    __shared__ float tile[64][65];
    const int b  = blockIdx.y;
    const int n0 = blockIdx.x * 64;
    const int t  = threadIdx.x;
    const int c  = t & 63;
    const int dn = t >> 6;
#pragma unroll
    for (int i = 0; i < 16; ++i) {
        int nl = dn + i * 4;
        tile[c][nl] = x[((size_t)b * 512 + n0 + nl) * 64 + c];
    }
    __syncthreads();
    const int nl = t & 63;
    const int cb = (t >> 6) * 16;
#pragma unroll
    for (int i = 0; i < 16; ++i) {
        int c2 = cb + i;
        xm[((size_t)b * 64 + c2) * 512 + n0 + nl] = tile[c2][nl];
    }
}

// ---------------- proj[b,a] = occ[b,:] . proj_w[a,:] + proj_b[a]
__global__ __launch_bounds__(64) void k_proj(const float* __restrict__ occ, const float* __restrict__ pw,
                                             const float* __restrict__ pb, float* __restrict__ proj) {
    const int b = blockIdx.x;
    const int a = threadIdx.x;
    const float* ob = occ + (size_t)b * 512;
    const float* wr = pw + (size_t)a * 512;
    float acc = 0.f;
    for (int n = 0; n < 512; ++n) acc += ob[n] * wr[n];
    proj[b * 64 + a] = acc + pb[a];
}

// ---------------- m1,m2 per (b,c): gate scalars
__global__ __launch_bounds__(64) void k_m(const float* __restrict__ xm,
                                          const float* __restrict__ g1w, const float* __restrict__ g1b,
                                          const float* __restrict__ g2w, const float* __restrict__ g2b,
                                          const float* __restrict__ proj, float* __restrict__ m1m2) {
    const int r = blockIdx.x;          // b*64+c
    const int b = r >> 6, c = r & 63;
    const int lane = threadIdx.x;
    const float* row = xm + (size_t)r * 512;
    float a1 = 0.f, a2 = 0.f;
    for (int n = lane; n < 512; n += 64) {
        float xv = row[n];
        a1 += xv * g1w[n];
        a2 += xv * g2w[n];
    }
    a1 += proj[b * 64 + lane] * g1w[512 + lane];   // AATE part: per-a
    a2 += proj[b * 64 + c]    * g2w[512 + lane];   // AATE_T part: proj[b,c]*sum_a g2w
    for (int off = 32; off; off >>= 1) { a1 += __shfl_xor(a1, off); a2 += __shfl_xor(a2, off); }
    if (lane == 0) {
        float m1 = tanhf(a1 + g1b[0]); m1 = m1 > 0.f ? m1 : 0.f;
        float m2 = tanhf(a2 + g2b[0]); m2 = m2 > 0.f ? m2 : 0.f;
        m1m2[2 * r] = m1; m1m2[2 * r + 1] = m2;
    }
}

// ---------------- P-kernel: vbuf[r,0:64]=v1, [64:128]=v2 -> in-place P1,P2
__global__ __launch_bounds__(64) void k_p(float* __restrict__ vb, const float* __restrict__ m1m2,
                                          const float* __restrict__ proj) {
    const int r = blockIdx.x;
    const int b = r >> 6, c = r & 63;
    const int a = threadIdx.x;
    const float m1 = m1m2[2 * r], m2 = m1m2[2 * r + 1];
    float s1 = m1 * vb[(size_t)r * 128 + a];       s1 = s1 > 0.f ? s1 : 0.f;
    float s2 = m2 * vb[(size_t)r * 128 + 64 + a];  s2 = s2 > 0.f ? s2 : 0.f;
    float mx1 = s1, mx2 = s2;
    for (int off = 32; off; off >>= 1) { mx1 = fmaxf(mx1, __shfl_xor(mx1, off)); mx2 = fmaxf(mx2, __shfl_xor(mx2, off)); }
    float e1 = expf(s1 - mx1), e2 = expf(s2 - mx2);
    float su1 = e1, su2 = e2;
    for (int off = 32; off; off >>= 1) { su1 += __shfl_xor(su1, off); su2 += __shfl_xor(su2, off); }
    vb[(size_t)r * 128 + a]      = proj[b * 64 + a] + e1 / su1;   // P1[b,c,a]
    vb[(size_t)r * 128 + 64 + a] = proj[b * 64 + c] + e2 / su2;   // P2[b,c,a]
}

// ---------------- adp[b,c,c'] = softmax_{c'} relu( sum_a P1[b,c,a]*P2[b,c',a] )
__global__ __launch_bounds__(256) void k_adp(const float* __restrict__ vb, float* __restrict__ adp) {
    __shared__ float P1s[64][64];
    __shared__ float P2s[64][65];
    const int b = blockIdx.x;
    const int t = threadIdx.x;
#pragma unroll
    for (int i = 0; i < 16; ++i) {
        int idx = t + 256 * i;          // 0..4095
        int c = idx >> 6, a = idx & 63;
        P1s[c][a] = vb[((size_t)b * 64 + c) * 128 + a];
        P2s[c][a] = vb[((size_t)b * 64 + c) * 128 + 64 + a];
    }
    __syncthreads();
    const int lane = t & 63;   // c'
    const int w = t >> 6;
    for (int ci = 0; ci < 16; ++ci) {
        int c = w + ci * 4;
        float s = 0.f;
        for (int a = 0; a < 64; ++a) s += P1s[c][a] * P2s[lane][a];
        s = fmaxf(s, 0.f);
        float mx = s;
        for (int off = 32; off; off >>= 1) mx = fmaxf(mx, __shfl_xor(mx, off));
        float e = expf(s - mx);
        float su = e;
        for (int off = 32; off; off >>= 1) su += __shfl_xor(su, off);
        adp[((size_t)b * 64 + c) * 64 + lane] = e / su;
    }
}

// ---------------- nconv: out[(b*64+v)*512+n] = sum_c adp[b,c,v] * X[(b*64+c)*512+n]
__global__ __launch_bounds__(256) void k_nconv(const float* __restrict__ X, const float* __restrict__ adp,
                                               float* __restrict__ out) {
    __shared__ float As[16][64];     // [c-local][v]
    __shared__ float Bs[16][128];    // [c-local][n-local]
    const int b  = blockIdx.y;
    const int n0 = blockIdx.x * 128;
    const int t  = threadIdx.x;
    const int tx = t & 15, ty = t >> 4;
    const int cl = t >> 4;
    const int v4 = (t & 15) * 4;
    const int n8 = (t & 15) * 8;
    float acc[4][8] = {};
    for (int c0 = 0; c0 < 64; c0 += 16) {
        *(float4*)&As[cl][v4] = *(const float4*)(adp + ((size_t)b * 64 + c0 + cl) * 64 + v4);
        const float* xr = X + ((size_t)b * 64 + c0 + cl) * 512 + n0 + n8;
        *(float4*)&Bs[cl][n8]     = *(const float4*)(xr);
        *(float4*)&Bs[cl][n8 + 4] = *(const float4*)(xr + 4);
        __syncthreads();
#pragma unroll
        for (int kk = 0; kk < 16; ++kk) {
            float4 a4 = *(const float4*)&As[kk][ty * 4];
            float4 b0 = *(const float4*)&Bs[kk][tx * 4];
            float4 b1 = *(const float4*)&Bs[kk][64 + tx * 4];
            const float av[4] = {a4.x, a4.y, a4.z, a4.w};
            const float bv[8] = {b0.x, b0.y, b0.z, b0.w, b1.x, b1.y, b1.z, b1.w};
#pragma unroll
            for (int i = 0; i < 4; ++i)
#pragma unroll
                for (int j = 0; j < 8; ++j) acc[i][j] += av[i] * bv[j];
        }
        __syncthreads();
    }
#pragma unroll
    for (int i = 0; i < 4; ++i) {
        int v = ty * 4 + i;
        float4 o0 = {acc[i][0], acc[i][1], acc[i][2], acc[i][3]};
        float4 o1 = {acc[i][4], acc[i][5], acc[i][6], acc[i][7]};
        *(float4*)(out + ((size_t)b * 64 + v) * 512 + n0 + tx * 4)      = o0;
        *(float4*)(out + ((size_t)b * 64 + v) * 512 + n0 + 64 + tx * 4) = o1;
    }
}

// ---------------- generic GEMM: out[m,n] = act( sum_k A[m,k]*W[n,k] + bias[n] ) (+ res[m,n])
// A segments each have row stride 512; segment s covers k in [512s, 512s+512).
// W rows: n < nsplit -> W0 row n ; else W1 row (n-nsplit). Row stride = K.
template<int BM, int BN, int TM, int TN>
__global__ __launch_bounds__(256) void gemm_kernel(
    const float* __restrict__ A0, const float* __restrict__ A1, const float* __restrict__ A2,
    const float* __restrict__ W0, const float* __restrict__ W1, int nsplit,
    const float* __restrict__ bias0, const float* __restrict__ bias1,
    const float* __restrict__ res, float* __restrict__ out,
    int M, int N, int K, int relu)
{
    constexpr int BK = 16;
    __shared__ float As[BK][BM];
    __shared__ float Bs[BK][BN];
    const int t  = threadIdx.x;
    const int m0 = blockIdx.x * BM;
    const int n0 = blockIdx.y * BN;
    const int tx = t & 15;
    const int ty = t >> 4;
    const int lr = t & 63;           // load row within 64-group
    const int lk = (t >> 6) * 4;     // k-subgroup per wave
    float acc[TM][TN] = {};

    for (int k0 = 0; k0 < K; k0 += BK) {
        const int seg = k0 >> 9;
        const float* Aseg = (seg == 0) ? A0 : ((seg == 1) ? A1 : A2);
        const int kloc = k0 & 511;
#pragma unroll
        for (int r = 0; r < BM; r += 64) {
            float4 v = *(const float4*)(Aseg + (size_t)(m0 + r + lr) * 512 + kloc + lk);
            As[lk + 0][r + lr] = v.x; As[lk + 1][r + lr] = v.y;
            As[lk + 2][r + lr] = v.z; As[lk + 3][r + lr] = v.w;
        }
#pragma unroll
        for (int r = 0; r < BN; r += 64) {
            int n = n0 + r + lr;
            const float* Wr = (n < nsplit) ? (W0 + (size_t)n * K) : (W1 + (size_t)(n - nsplit) * K);
            float4 wv = *(const float4*)(Wr + k0 + lk);
            Bs[lk + 0][r + lr] = wv.x; Bs[lk + 1][r + lr] = wv.y;
            Bs[lk + 2][r + lr] = wv.z; Bs[lk + 3][r + lr] = wv.w;
        }
        __syncthreads();
#pragma unroll
        for (int kk = 0; kk < BK; ++kk) {
            float a[TM], bb[TN];
            if constexpr (TM == 8) {
                *(float4*)&a[0] = *(const float4*)&As[kk][ty * 8];
                *(float4*)&a[4] = *(const float4*)&As[kk][ty * 8 + 4];
            } else {
                *(float4*)&a[0] = *(const float4*)&As[kk][ty * 4];
            }
            if constexpr (TN == 8) {
                *(float4*)&bb[0] = *(const float4*)&Bs[kk][tx * 4];
                *(float4*)&bb[4] = *(const float4*)&Bs[kk][64 + tx * 4];
            } else {
                *(float4*)&bb[0] = *(const float4*)&Bs[kk][tx * 4];
            }
#pragma unroll
            for (int i = 0; i < TM; ++i)
#pragma unroll
                for (int j = 0; j < TN; ++j) acc[i][j] += a[i] * bb[j];
        }
        __syncthreads();
    }
#pragma unroll
    for (int i = 0; i < TM; ++i) {
        int m = m0 + ((TM == 8) ? (ty * 8 + i) : (ty * 4 + i));
#pragma unroll
        for (int j = 0; j < TN; ++j) {
            int n;
            if constexpr (TN == 8) n = n0 + ((j < 4) ? (tx * 4 + j) : (64 + tx * 4 + (j - 4)));
            else                   n = n0 + tx * 4 + j;
            float bv = (n < nsplit) ? bias0[n] : bias1[n - nsplit];
            float v = acc[i][j] + bv;
            if (relu) v = fmaxf(v, 0.f);
            if (res) v += res[(size_t)m * N + n];
            out[(size_t)m * N + n] = v;
        }
    }
}

// ---------------- dvec[r] = t[r,:] . d2_w + d2_b   (t rows of 256)
__global__ __launch_bounds__(256) void k_dvec(const float* __restrict__ tmat, const float* __restrict__ d2w,
                                              const float* __restrict__ d2b, float* __restrict__ dvec) {
    const int r = blockIdx.x * 4 + (threadIdx.x >> 6);
    const int lane = threadIdx.x & 63;
    const float* row = tmat + (size_t)r * 256;
    float acc = 0.f;
    for (int f = lane; f < 256; f += 64) acc += row[f] * d2w[f];
    for (int off = 32; off; off >>= 1) acc += __shfl_xor(acc, off);
    if (lane == 0) dvec[r] = acc + d2b[0];
}

// ---------------- channel decoder + abs -> out[b] (f32)
__global__ __launch_bounds__(64) void k_final(const float* __restrict__ dvec, const float* __restrict__ c1w,
                                              const float* __restrict__ c1b, const float* __restrict__ c2w,
                                              const float* __restrict__ c2b, float* __restrict__ out) {
    const int b = blockIdx.x;
    const int f = threadIdx.x;
    float part = 0.f;
    if (f < 32) {
        float acc = c1b[f];
        const float* dr = dvec + b * 64;
        for (int c = 0; c < 64; ++c) acc += dr[c] * c1w[f * 64 + c];
        acc = acc > 0.f ? acc : 0.f;
        part = acc * c2w[f];
    }
    for (int off = 32; off; off >>= 1) part += __shfl_xor(part, off);
    if (f == 0) out[b] = fabsf(part + c2b[0]);
}

extern "C" void kernel_launch(void* const* d_in, const int* in_sizes, int n_in,
                              void* d_out, int out_size, void* d_ws, size_t ws_size,
                              hipStream_t stream) {
    const float* x     = (const float*)d_in[0];
    const float* occ   = (const float*)d_in[1];
    const float* projw = (const float*)d_in[2];
    const float* projb = (const float*)d_in[3];
    const float* ll1w  = (const float*)d_in[4];
    const float* ll1b  = (const float*)d_in[5];
    const float* ll2w  = (const float*)d_in[6];
    const float* ll2b  = (const float*)d_in[7];
    const float* g1w   = (const float*)d_in[8];
    const float* g1b   = (const float*)d_in[9];
    const float* g2w   = (const float*)d_in[10];
    const float* g2b   = (const float*)d_in[11];
    const float* gcw   = (const float*)d_in[12];
    const float* gcb   = (const float*)d_in[13];
    const float* taw   = (const float*)d_in[14];
    const float* tab   = (const float*)d_in[15];
    const float* d1w   = (const float*)d_in[16];
    const float* d1b   = (const float*)d_in[17];
    const float* d2w   = (const float*)d_in[18];
    const float* d2b   = (const float*)d_in[19];
    const float* c1w   = (const float*)d_in[20];
    const float* c1b   = (const float*)d_in[21];
    const float* c2w   = (const float*)d_in[22];
    const float* c2b   = (const float*)d_in[23];

    float* ws   = (float*)d_ws;
    float* xmA  = ws;                                  // 16384*512
    float* xmB  = xmA  + (size_t)16384 * 512;
    float* x1T  = xmB  + (size_t)16384 * 512;
    float* x2T  = x1T  + (size_t)16384 * 512;
    float* vbuf = x2T  + (size_t)16384 * 512;          // 16384*128 (v1|v2 -> P1|P2)
    float* adp  = vbuf + (size_t)16384 * 128;          // 16384*64
    float* proj = adp  + (size_t)16384 * 64;           // 16384
    float* m1m2 = proj + 16384;                        // 32768
    float* dvec = m1m2 + 32768;                        // 16384

    k_transpose<<<dim3(8, 256), 256, 0, stream>>>(x, xmA);
    k_proj<<<256, 64, 0, stream>>>(occ, projw, projb, proj);

    float* cur = xmA;
    float* nxt = xmB;
    for (int l = 0; l < 3; ++l) {
        k_m<<<16384, 64, 0, stream>>>(cur, g1w + l * 576, g1b + l, g2w + l * 576, g2b + l, proj, m1m2);
        gemm_kernel<64, 128, 4, 8><<<dim3(256, 1), 256, 0, stream>>>(
            cur, nullptr, nullptr,
            ll1w + (size_t)l * 64 * 512, ll2w + (size_t)l * 64 * 512, 64,
            ll1b + l * 64, ll2b + l * 64, nullptr, vbuf, 16384, 128, 512, 0);
        k_p<<<16384, 64, 0, stream>>>(vbuf, m1m2, proj);
        k_adp<<<256, 256, 0, stream>>>(vbuf, adp);
        k_nconv<<<dim3(4, 256), 256, 0, stream>>>(cur, adp, x1T);
        k_nconv<<<dim3(4, 256), 256, 0, stream>>>(x1T, adp, x2T);
        gemm_kernel<128, 128, 8, 8><<<dim3(128, 4), 256, 0, stream>>>(
            cur, x1T, x2T,
            gcw + (size_t)l * 512 * 1536, gcw + (size_t)l * 512 * 1536, 512,
            gcb + l * 512, gcb + l * 512, (l > 0 ? cur : nullptr), nxt, 16384, 512, 1536, 1);
        float* tmp = cur; cur = nxt; nxt = tmp;
    }
    // temporal_agg: z2 = xm @ ta_w^T + ta_b  -> reuse x1T
    gemm_kernel<128, 128, 8, 8><<<dim3(128, 4), 256, 0, stream>>>(
        cur, nullptr, nullptr, taw, taw, 512, tab, tab, nullptr, x1T, 16384, 512, 512, 0);
    // decoder 1: t = relu(z2 @ d1_w^T + d1_b) -> reuse x2T
    gemm_kernel<128, 128, 8, 8><<<dim3(128, 2), 256, 0, stream>>>(
        x1T, nullptr, nullptr, d1w, d1w, 256, d1b, d1b, nullptr, x2T, 16384, 256, 512, 1);
    k_dvec<<<4096, 256, 0, stream>>>(x2T, d2w, d2b, dvec);
    k_final<<<256, 64, 0, stream>>>(dvec, c1w, c1b, c2w, c2b, (float*)d_out);
}

// Round 3
// 683.329 us; speedup vs baseline: 2.5148x; 2.5148x over previous
//
#include <hip/hip_runtime.h>

typedef unsigned short u16;
typedef __attribute__((ext_vector_type(8))) short short8;   // 8 bf16
typedef __attribute__((ext_vector_type(4))) float f32x4;

// B=256, N=H=512, C=A=64, L=3, FC=256, FFC=32.  M := B*C = 16384 rows of xm.
// fp32 master copies + bf16 shadow copies for MFMA GEMM inputs.

__device__ __forceinline__ u16 f2b(float f) {
    union { float f; unsigned int i; } v; v.f = f;
    unsigned int x = v.i;
    x += 0x7fffu + ((x >> 16) & 1u);   // RNE
    return (u16)(x >> 16);
}

// ---------------- fp32 -> bf16 weight conversion (16B vectorized)
__global__ __launch_bounds__(256) void k_cvt(const float* __restrict__ src, u16* __restrict__ dst, int n4) {
    int i = blockIdx.x * 256 + threadIdx.x;
    if (i < n4) {
        float4 v = ((const float4*)src)[i];
        ushort4 o; o.x = f2b(v.x); o.y = f2b(v.y); o.z = f2b(v.z); o.w = f2b(v.w);
        ((ushort4*)dst)[i] = o;
    }
}

// ---------------- transpose: x[b,n,c] (f32) -> xm[(b*64+c)*512+n] f32 + bf16
__global__ __launch_bounds__(256) void k_transpose(const float* __restrict__ x, float* __restrict__ xm,
                                                   u16* __restrict__ xmb) {
    __shared__ float tile[64][65];
    const int b  = blockIdx.y;
    const int n0 = blockIdx.x * 64;
    const int t  = threadIdx.x;
    const int c  = t & 63;
    const int dn = t >> 6;
#pragma unroll
    for (int i = 0; i < 16; ++i) {
        int nl = dn + i * 4;
        tile[c][nl] = x[((size_t)b * 512 + n0 + nl) * 64 + c];
    }
    __syncthreads();
    const int nl = t & 63;
    const int cb = (t >> 6) * 16;
#pragma unroll
    for (int i = 0; i < 16; ++i) {
        int c2 = cb + i;
        float v = tile[c2][nl];
        size_t idx = ((size_t)b * 64 + c2) * 512 + n0 + nl;
        xm[idx] = v;
        xmb[idx] = f2b(v);
    }
}

// ---------------- proj[b,a] = occ[b,:] . proj_w[a,:] + proj_b[a]
__global__ __launch_bounds__(64) void k_proj(const float* __restrict__ occ, const float* __restrict__ pw,
                                             const float* __restrict__ pb, float* __restrict__ proj) {
    const int b = blockIdx.x;
    const int a = threadIdx.x;
    const float* ob = occ + (size_t)b * 512;
    const float* wr = pw + (size_t)a * 512;
    float acc = 0.f;
    for (int n = 0; n < 512; ++n) acc += ob[n] * wr[n];
    proj[b * 64 + a] = acc + pb[a];
}

// ---------------- m1,m2 per (b,c): gate scalars
__global__ __launch_bounds__(64) void k_m(const float* __restrict__ xm,
                                          const float* __restrict__ g1w, const float* __restrict__ g1b,
                                          const float* __restrict__ g2w, const float* __restrict__ g2b,
                                          const float* __restrict__ proj, float* __restrict__ m1m2) {
    const int r = blockIdx.x;          // b*64+c
    const int b = r >> 6, c = r & 63;
    const int lane = threadIdx.x;
    const float* row = xm + (size_t)r * 512;
    float a1 = 0.f, a2 = 0.f;
    for (int n = lane; n < 512; n += 64) {
        float xv = row[n];
        a1 += xv * g1w[n];
        a2 += xv * g2w[n];
    }
    a1 += proj[b * 64 + lane] * g1w[512 + lane];
    a2 += proj[b * 64 + c]    * g2w[512 + lane];
    for (int off = 32; off; off >>= 1) { a1 += __shfl_xor(a1, off); a2 += __shfl_xor(a2, off); }
    if (lane == 0) {
        float m1 = tanhf(a1 + g1b[0]); m1 = m1 > 0.f ? m1 : 0.f;
        float m2 = tanhf(a2 + g2b[0]); m2 = m2 > 0.f ? m2 : 0.f;
        m1m2[2 * r] = m1; m1m2[2 * r + 1] = m2;
    }
}

// ---------------- P-kernel
__global__ __launch_bounds__(64) void k_p(float* __restrict__ vb, const float* __restrict__ m1m2,
                                          const float* __restrict__ proj) {
    const int r = blockIdx.x;
    const int b = r >> 6, c = r & 63;
    const int a = threadIdx.x;
    const float m1 = m1m2[2 * r], m2 = m1m2[2 * r + 1];
    float s1 = m1 * vb[(size_t)r * 128 + a];       s1 = s1 > 0.f ? s1 : 0.f;
    float s2 = m2 * vb[(size_t)r * 128 + 64 + a];  s2 = s2 > 0.f ? s2 : 0.f;
    float mx1 = s1, mx2 = s2;
    for (int off = 32; off; off >>= 1) { mx1 = fmaxf(mx1, __shfl_xor(mx1, off)); mx2 = fmaxf(mx2, __shfl_xor(mx2, off)); }
    float e1 = expf(s1 - mx1), e2 = expf(s2 - mx2);
    float su1 = e1, su2 = e2;
    for (int off = 32; off; off >>= 1) { su1 += __shfl_xor(su1, off); su2 += __shfl_xor(su2, off); }
    vb[(size_t)r * 128 + a]      = proj[b * 64 + a] + e1 / su1;
    vb[(size_t)r * 128 + 64 + a] = proj[b * 64 + c] + e2 / su2;
}

// ---------------- adp
__global__ __launch_bounds__(256) void k_adp(const float* __restrict__ vb, float* __restrict__ adp) {
    __shared__ float P1s[64][64];
    __shared__ float P2s[64][65];
    const int b = blockIdx.x;
    const int t = threadIdx.x;
#pragma unroll
    for (int i = 0; i < 16; ++i) {
        int idx = t + 256 * i;
        int c = idx >> 6, a = idx & 63;
        P1s[c][a] = vb[((size_t)b * 64 + c) * 128 + a];
        P2s[c][a] = vb[((size_t)b * 64 + c) * 128 + 64 + a];
    }
    __syncthreads();
    const int lane = t & 63;
    const int w = t >> 6;
    for (int ci = 0; ci < 16; ++ci) {
        int c = w + ci * 4;
        float s = 0.f;
        for (int a = 0; a < 64; ++a) s += P1s[c][a] * P2s[lane][a];
        s = fmaxf(s, 0.f);
        float mx = s;
        for (int off = 32; off; off >>= 1) mx = fmaxf(mx, __shfl_xor(mx, off));
        float e = expf(s - mx);
        float su = e;
        for (int off = 32; off; off >>= 1) su += __shfl_xor(su, off);
        adp[((size_t)b * 64 + c) * 64 + lane] = e / su;
    }
}

// ---------------- nconv: out fp32 + bf16 shadow
__global__ __launch_bounds__(256) void k_nconv(const float* __restrict__ X, const float* __restrict__ adp,
                                               float* __restrict__ out, u16* __restrict__ outb) {
    __shared__ float As[16][64];
    __shared__ float Bs[16][128];
    const int b  = blockIdx.y;
    const int n0 = blockIdx.x * 128;
    const int t  = threadIdx.x;
    const int tx = t & 15, ty = t >> 4;
    const int cl = t >> 4;
    const int v4 = (t & 15) * 4;
    const int n8 = (t & 15) * 8;
    float acc[4][8] = {};
    for (int c0 = 0; c0 < 64; c0 += 16) {
        *(float4*)&As[cl][v4] = *(const float4*)(adp + ((size_t)b * 64 + c0 + cl) * 64 + v4);
        const float* xr = X + ((size_t)b * 64 + c0 + cl) * 512 + n0 + n8;
        *(float4*)&Bs[cl][n8]     = *(const float4*)(xr);
        *(float4*)&Bs[cl][n8 + 4] = *(const float4*)(xr + 4);
        __syncthreads();
#pragma unroll
        for (int kk = 0; kk < 16; ++kk) {
            float4 a4 = *(const float4*)&As[kk][ty * 4];
            float4 b0 = *(const float4*)&Bs[kk][tx * 4];
            float4 b1 = *(const float4*)&Bs[kk][64 + tx * 4];
            const float av[4] = {a4.x, a4.y, a4.z, a4.w};
            const float bv[8] = {b0.x, b0.y, b0.z, b0.w, b1.x, b1.y, b1.z, b1.w};
#pragma unroll
            for (int i = 0; i < 4; ++i)
#pragma unroll
                for (int j = 0; j < 8; ++j) acc[i][j] += av[i] * bv[j];
        }
        __syncthreads();
    }
#pragma unroll
    for (int i = 0; i < 4; ++i) {
        int v = ty * 4 + i;
        size_t base = ((size_t)b * 64 + v) * 512 + n0;
        float4 o0 = {acc[i][0], acc[i][1], acc[i][2], acc[i][3]};
        float4 o1 = {acc[i][4], acc[i][5], acc[i][6], acc[i][7]};
        *(float4*)(out + base + tx * 4)      = o0;
        *(float4*)(out + base + 64 + tx * 4) = o1;
        ushort4 u0; u0.x = f2b(o0.x); u0.y = f2b(o0.y); u0.z = f2b(o0.z); u0.w = f2b(o0.w);
        ushort4 u1; u1.x = f2b(o1.x); u1.y = f2b(o1.y); u1.z = f2b(o1.z); u1.w = f2b(o1.w);
        *(ushort4*)(outb + base + tx * 4)      = u0;
        *(ushort4*)(outb + base + 64 + tx * 4) = u1;
    }
}

// ---------------- MFMA GEMM: out[m,n] = act( sum_k A[m,k]*W[n,k] + bias[n] ) (+res), A/W bf16
// A segments (stride 512) cover k in [512s, 512s+512).  W rows: n<nsplit -> W0 else W1 (stride K).
// Block tile 128x128, 4 waves (2x2 of 64x64), 16x16x32 MFMA, BK=32.
__global__ __launch_bounds__(256) void mfma_gemm(
    const u16* __restrict__ A0, const u16* __restrict__ A1, const u16* __restrict__ A2,
    const u16* __restrict__ W0, const u16* __restrict__ W1, int nsplit,
    const float* __restrict__ bias0, const float* __restrict__ bias1,
    const float* __restrict__ res, float* __restrict__ out, u16* __restrict__ outbf,
    int N, int K, int relu)
{
    __shared__ __align__(16) u16 As[128 * 40];   // row stride 40 shorts (pad 8) -> conflict-light
    __shared__ __align__(16) u16 Bs[128 * 40];
    const int t    = threadIdx.x;
    const int m0   = blockIdx.x * 128;
    const int n0   = blockIdx.y * 128;
    const int lane = t & 63;
    const int w    = t >> 6;
    const int wm   = (w >> 1) * 64;
    const int wn   = (w & 1) * 64;
    const int lrow = lane & 15;
    const int q    = lane >> 4;

    const int srow = t >> 2;      // 0..63 (and +64)
    const int skq  = t & 3;       // 16B chunk within 64B row

    const f32x4 zero = {0.f, 0.f, 0.f, 0.f};
    f32x4 acc[4][4];
#pragma unroll
    for (int i = 0; i < 4; ++i)
#pragma unroll
        for (int j = 0; j < 4; ++j) acc[i][j] = zero;

    for (int k0 = 0; k0 < K; k0 += 32) {
        const u16* Abase = A0;
        int kloc = k0;
        if (K > 512) {
            int seg = k0 >> 9;
            Abase = (seg == 0) ? A0 : ((seg == 1) ? A1 : A2);
            kloc = k0 & 511;
        }
        // stage A (two rows per thread)
        uint4 a0 = *(const uint4*)(Abase + (size_t)(m0 + srow) * 512 + kloc + skq * 8);
        uint4 a1 = *(const uint4*)(Abase + (size_t)(m0 + srow + 64) * 512 + kloc + skq * 8);
        // stage B
        int na = n0 + srow, nb = n0 + srow + 64;
        const u16* wr0 = (na < nsplit) ? (W0 + (size_t)na * K) : (W1 + (size_t)(na - nsplit) * K);
        const u16* wr1 = (nb < nsplit) ? (W0 + (size_t)nb * K) : (W1 + (size_t)(nb - nsplit) * K);
        uint4 b0 = *(const uint4*)(wr0 + k0 + skq * 8);
        uint4 b1 = *(const uint4*)(wr1 + k0 + skq * 8);
        *(uint4*)&As[srow * 40 + skq * 8]        = a0;
        *(uint4*)&As[(srow + 64) * 40 + skq * 8] = a1;
        *(uint4*)&Bs[srow * 40 + skq * 8]        = b0;
        *(uint4*)&Bs[(srow + 64) * 40 + skq * 8] = b1;
        __syncthreads();

        short8 af[4], bfr[4];
#pragma unroll
        for (int mt = 0; mt < 4; ++mt)
            af[mt] = *(const short8*)&As[(wm + mt * 16 + lrow) * 40 + q * 8];
#pragma unroll
        for (int nt = 0; nt < 4; ++nt)
            bfr[nt] = *(const short8*)&Bs[(wn + nt * 16 + lrow) * 40 + q * 8];
#pragma unroll
        for (int mt = 0; mt < 4; ++mt)
#pragma unroll
            for (int nt = 0; nt < 4; ++nt)
                acc[mt][nt] = __builtin_amdgcn_mfma_f32_16x16x32_bf16(af[mt], bfr[nt], acc[mt][nt], 0, 0, 0);
        __syncthreads();
    }

#pragma unroll
    for (int mt = 0; mt < 4; ++mt) {
        int mb = m0 + wm + mt * 16 + q * 4;
#pragma unroll
        for (int nt = 0; nt < 4; ++nt) {
            int n = n0 + wn + nt * 16 + lrow;
            float bv = (n < nsplit) ? bias0[n] : bias1[n - nsplit];
#pragma unroll
            for (int i = 0; i < 4; ++i) {
                float v = acc[mt][nt][i] + bv;
                if (relu) v = fmaxf(v, 0.f);
                if (res) v += res[(size_t)(mb + i) * N + n];
                out[(size_t)(mb + i) * N + n] = v;
                if (outbf) outbf[(size_t)(mb + i) * N + n] = f2b(v);
            }
        }
    }
}

// ---------------- dvec[r] = t[r,:256] . d2_w + d2_b
__global__ __launch_bounds__(256) void k_dvec(const float* __restrict__ tmat, const float* __restrict__ d2w,
                                              const float* __restrict__ d2b, float* __restrict__ dvec) {
    const int r = blockIdx.x * 4 + (threadIdx.x >> 6);
    const int lane = threadIdx.x & 63;
    const float* row = tmat + (size_t)r * 256;
    float acc = 0.f;
    for (int f = lane; f < 256; f += 64) acc += row[f] * d2w[f];
    for (int off = 32; off; off >>= 1) acc += __shfl_xor(acc, off);
    if (lane == 0) dvec[r] = acc + d2b[0];
}

// ---------------- channel decoder + abs
__global__ __launch_bounds__(64) void k_final(const float* __restrict__ dvec, const float* __restrict__ c1w,
                                              const float* __restrict__ c1b, const float* __restrict__ c2w,
                                              const float* __restrict__ c2b, float* __restrict__ out) {
    const int b = blockIdx.x;
    const int f = threadIdx.x;
    float part = 0.f;
    if (f < 32) {
        float acc = c1b[f];
        const float* dr = dvec + b * 64;
        for (int c = 0; c < 64; ++c) acc += dr[c] * c1w[f * 64 + c];
        acc = acc > 0.f ? acc : 0.f;
        part = acc * c2w[f];
    }
    for (int off = 32; off; off >>= 1) part += __shfl_xor(part, off);
    if (f == 0) out[b] = fabsf(part + c2b[0]);
}

extern "C" void kernel_launch(void* const* d_in, const int* in_sizes, int n_in,
                              void* d_out, int out_size, void* d_ws, size_t ws_size,
                              hipStream_t stream) {
    const float* x     = (const float*)d_in[0];
    const float* occ   = (const float*)d_in[1];
    const float* projw = (const float*)d_in[2];
    const float* projb = (const float*)d_in[3];
    const float* ll1w  = (const float*)d_in[4];
    const float* ll1b  = (const float*)d_in[5];
    const float* ll2w  = (const float*)d_in[6];
    const float* ll2b  = (const float*)d_in[7];
    const float* g1w   = (const float*)d_in[8];
    const float* g1b   = (const float*)d_in[9];
    const float* g2w   = (const float*)d_in[10];
    const float* g2b   = (const float*)d_in[11];
    const float* gcw   = (const float*)d_in[12];
    const float* gcb   = (const float*)d_in[13];
    const float* taw   = (const float*)d_in[14];
    const float* tab   = (const float*)d_in[15];
    const float* d1w   = (const float*)d_in[16];
    const float* d1b   = (const float*)d_in[17];
    const float* d2w   = (const float*)d_in[18];
    const float* d2b   = (const float*)d_in[19];
    const float* c1w   = (const float*)d_in[20];
    const float* c1b   = (const float*)d_in[21];
    const float* c2w   = (const float*)d_in[22];
    const float* c2b   = (const float*)d_in[23];

    const size_t MR = (size_t)16384 * 512;   // 8388608
    float* ws   = (float*)d_ws;
    float* xmA  = ws;
    float* xmB  = xmA + MR;
    float* x1T  = xmB + MR;
    float* x2T  = x1T + MR;
    float* vbuf = x2T + MR;                   // 16384*128
    float* adp  = vbuf + (size_t)16384 * 128; // 16384*64
    float* proj = adp  + (size_t)16384 * 64;
    float* m1m2 = proj + 16384;
    float* dvec = m1m2 + 32768;
    u16* bfb    = (u16*)(dvec + 16384);
    u16* xmA_bf = bfb;
    u16* xmB_bf = xmA_bf + MR;
    u16* x1T_bf = xmB_bf + MR;
    u16* x2T_bf = x1T_bf + MR;
    u16* ll1w_bf = x2T_bf + MR;               // 3*64*512 = 98304
    u16* ll2w_bf = ll1w_bf + 98304;
    u16* gcw_bf  = ll2w_bf + 98304;           // 3*512*1536 = 2359296
    u16* taw_bf  = gcw_bf + 2359296;          // 262144
    u16* d1w_bf  = taw_bf + 262144;           // 131072

    // weight conversions (cheap, per-launch)
    k_cvt<<<96,   256, 0, stream>>>(ll1w, ll1w_bf, 98304 / 4);
    k_cvt<<<96,   256, 0, stream>>>(ll2w, ll2w_bf, 98304 / 4);
    k_cvt<<<2304, 256, 0, stream>>>(gcw,  gcw_bf,  2359296 / 4);
    k_cvt<<<256,  256, 0, stream>>>(taw,  taw_bf,  262144 / 4);
    k_cvt<<<128,  256, 0, stream>>>(d1w,  d1w_bf,  131072 / 4);

    k_transpose<<<dim3(8, 256), 256, 0, stream>>>(x, xmA, xmA_bf);
    k_proj<<<256, 64, 0, stream>>>(occ, projw, projb, proj);

    float* cur = xmA;  u16* cur_bf = xmA_bf;
    float* nxt = xmB;  u16* nxt_bf = xmB_bf;
    for (int l = 0; l < 3; ++l) {
        k_m<<<16384, 64, 0, stream>>>(cur, g1w + l * 576, g1b + l, g2w + l * 576, g2b + l, proj, m1m2);
        mfma_gemm<<<dim3(128, 1), 256, 0, stream>>>(
            cur_bf, nullptr, nullptr,
            ll1w_bf + (size_t)l * 64 * 512, ll2w_bf + (size_t)l * 64 * 512, 64,
            ll1b + l * 64, ll2b + l * 64, nullptr, vbuf, nullptr, 128, 512, 0);
        k_p<<<16384, 64, 0, stream>>>(vbuf, m1m2, proj);
        k_adp<<<256, 256, 0, stream>>>(vbuf, adp);
        k_nconv<<<dim3(4, 256), 256, 0, stream>>>(cur, adp, x1T, x1T_bf);
        k_nconv<<<dim3(4, 256), 256, 0, stream>>>(x1T, adp, x2T, x2T_bf);
        mfma_gemm<<<dim3(128, 4), 256, 0, stream>>>(
            cur_bf, x1T_bf, x2T_bf,
            gcw_bf + (size_t)l * 512 * 1536, gcw_bf + (size_t)l * 512 * 1536, 512,
            gcb + l * 512, gcb + l * 512, (l > 0 ? cur : nullptr), nxt, nxt_bf, 512, 1536, 1);
        { float* tf = cur; cur = nxt; nxt = tf; }
        { u16* tb = cur_bf; cur_bf = nxt_bf; nxt_bf = tb; }
    }
    // temporal_agg -> x1T (+bf16)
    mfma_gemm<<<dim3(128, 4), 256, 0, stream>>>(
        cur_bf, nullptr, nullptr, taw_bf, taw_bf, 512, tab, tab, nullptr, x1T, x1T_bf, 512, 512, 0);
    // decoder1 -> x2T (fp32 only)
    mfma_gemm<<<dim3(128, 2), 256, 0, stream>>>(
        x1T_bf, nullptr, nullptr, d1w_bf, d1w_bf, 256, d1b, d1b, nullptr, x2T, nullptr, 256, 512, 1);
    k_dvec<<<4096, 256, 0, stream>>>(x2T, d2w, d2b, dvec);
    k_final<<<256, 64, 0, stream>>>(dvec, c1w, c1b, c2w, c2b, (float*)d_out);
}